// Round 2
// baseline (357.594 us; speedup 1.0000x reference)
//
#include <hip/hip_runtime.h>

typedef __bf16 bf16x8 __attribute__((ext_vector_type(8)));
typedef float f32x4 __attribute__((ext_vector_type(4)));

__device__ __forceinline__ unsigned short f2bf(float f) {
    union { float f; unsigned u; } v; v.f = f;
    unsigned r = (v.u + 0x7FFFu + ((v.u >> 16) & 1u)) >> 16;
    return (unsigned short)r;
}

// ---- weight transpose/cast kernels ----
// W1 (119,1024) f32 -> W1T (1024 x 128) bf16, zero-padded K 119->128
__global__ void conv_w1(const float* __restrict__ W1, unsigned short* __restrict__ W1T) {
    int idx = blockIdx.x * 256 + threadIdx.x;     // 131072 total
    int h = idx >> 7, k = idx & 127;
    float v = (k < 119) ? W1[(size_t)k * 1024 + h] : 0.0f;
    W1T[idx] = f2bf(v);
}
// W2 (1024,256) f32 -> W2T (256 x 1024) bf16
__global__ void conv_w2(const float* __restrict__ W2, unsigned short* __restrict__ W2T) {
    int idx = blockIdx.x * 256 + threadIdx.x;     // 262144 total
    int n = idx >> 10, h = idx & 1023;
    W2T[idx] = f2bf(W2[(size_t)h * 256 + n]);
}

// ---- fused features + MLP ----
// 512 threads (8 waves), 128 rows/block. wave w: rows (w>>2)*64..+63, col-group w&3.
// Chunk loop pipelined: between barriers, phase B(c-1) and phase A(c) both run
// (independent: B reads Hs, A writes only registers). Hs stores sit alone in the
// short second segment. 16 chunks -> ~31 barriers but all heavy work is in one
// unconstrained region per chunk with 48 MFMAs + all global/LDS loads.
__global__ __launch_bounds__(512, 4) void mlp_fused(
    const float* __restrict__ hole, const float* __restrict__ board,
    const float* __restrict__ b1, const float* __restrict__ b2,
    const unsigned short* __restrict__ W1T, const unsigned short* __restrict__ W2T,
    float* __restrict__ out)
{
    __shared__ unsigned short Xs[128][136];   // 34816 B; stride 136 (=17*8): b128 reads at bank floor
    __shared__ unsigned short Hs[128][72];    // 18432 B; stride 72: reads at floor, writes 2-way (free)

    const int tid   = threadIdx.x;
    const int wv    = tid >> 6;
    const int lane  = tid & 63;
    const int q     = lane >> 4;
    const int l16   = lane & 15;
    const int R0    = (wv >> 2) * 64;   // row base of this wave's 64-row half
    const int nq    = wv & 3;           // col group
    const long r0   = (long)blockIdx.x * 128;

    // ---------------- feature extraction: thread t < 128 handles row r0+t ----------------
    if (tid < 128) {
        const long r = r0 + tid;
        const float4* hp = (const float4*)(hole + r * 52);
        const float4* bp = (const float4*)(board + r * 52);
        unsigned long long hm = 0ull, bm = 0ull;
        #pragma unroll
        for (int i = 0; i < 13; ++i) {
            float4 h4 = hp[i], b4 = bp[i];
            int base = i * 4;
            hm |= ((unsigned long long)(h4.x > 0.5f)) << (base + 0);
            hm |= ((unsigned long long)(h4.y > 0.5f)) << (base + 1);
            hm |= ((unsigned long long)(h4.z > 0.5f)) << (base + 2);
            hm |= ((unsigned long long)(h4.w > 0.5f)) << (base + 3);
            bm |= ((unsigned long long)(b4.x > 0.5f)) << (base + 0);
            bm |= ((unsigned long long)(b4.y > 0.5f)) << (base + 1);
            bm |= ((unsigned long long)(b4.z > 0.5f)) << (base + 2);
            bm |= ((unsigned long long)(b4.w > 0.5f)) << (base + 3);
        }
        const unsigned long long am = hm | bm;
        const int bcount = __popcll(bm);
        const int hcount = __popcll(hm);

        int pairs_b = 0, pairs_a = 0;
        bool trips_b = false, trips_a = false;
        unsigned prb = 0, pra = 0;
        #pragma unroll
        for (int rr = 0; rr < 13; ++rr) {
            int cb = __popc((unsigned)((bm >> (4 * rr)) & 0xFull));
            int ca = __popc((unsigned)((am >> (4 * rr)) & 0xFull));
            pairs_b += (cb >= 2); trips_b = trips_b || (cb >= 3); prb |= (unsigned)(cb > 0) << rr;
            pairs_a += (ca >= 2); trips_a = trips_a || (ca >= 3); pra |= (unsigned)(ca > 0) << rr;
        }
        const unsigned long long SM = 0x1111111111111ull;
        int bscm = 0, ascm = 0;
        #pragma unroll
        for (int s = 0; s < 4; ++s) {
            int bs = __popcll(bm & (SM << s));
            int as = __popcll(am & (SM << s));
            bscm = bs > bscm ? bs : bscm;
            ascm = as > ascm ? as : ascm;
        }
        float strength = trips_b ? 0.8f : (pairs_b >= 2 ? 0.6f : (pairs_b >= 1 ? 0.4f : 0.2f));
        if (bcount == 0) strength = 0.0f;
        float flush_b = (bscm >= 3 && bcount > 0) ? 1.0f : 0.0f;
        bool sb = false;
        #pragma unroll
        for (int i = 0; i < 13; ++i) sb = sb || (__popc((prb >> i) & 0x1Fu) >= 3);
        float straight_b = (sb && bcount > 0) ? 1.0f : 0.0f;
        float gr0 = (bcount == 0) ? 1.0f : 0.0f;
        float gr3 = (bcount == 3) ? 1.0f : 0.0f;
        float gr4 = (bcount == 4) ? 1.0f : 0.0f;
        float gr5 = (bcount == 5) ? 1.0f : 0.0f;
        float valid = (hcount >= 2 && bcount >= 1) ? 1.0f : 0.0f;
        float flush_draw = (ascm == 4) ? 1.0f : 0.0f;
        float flush_outs = fmaxf(0.0f, 13.0f - (float)ascm) * (1.0f / 13.0f);
        int first = -1;
        #pragma unroll
        for (int i = 0; i < 13; ++i) {
            bool qq = (((pra >> i) & 1u) != 0u) && (__popc((pra >> i) & 0x1Fu) >= 4);
            if (qq && first < 0) first = i;
        }
        float straight_draw = (first >= 0) ? 1.0f : 0.0f;
        float straight_outs = 0.0f;
        if (first >= 0) {
            int c4 = __popc((pra >> first) & 0xFu);
            straight_outs = (c4 >= 4) ? 0.4f : 0.2f;
        }
        float total_outs = flush_draw * flush_outs * 9.0f + straight_draw * straight_outs * 8.0f;
        float remaining = 52.0f - (float)(hcount + bcount);
        float equity = 0.0f;
        if (remaining > 0.0f) equity = fminf(1.0f, total_outs / fmaxf(remaining, 1.0f));
        float hit_pair  = (pairs_a >= 1) ? 1.0f : 0.0f;
        float hit_trips = trips_a ? 1.0f : 0.0f;
        float hit_two   = (pairs_a >= 2) ? 1.0f : 0.0f;

        unsigned short* xrow = &Xs[tid][0];
        #pragma unroll
        for (int i = 0; i < 52; ++i) xrow[i]      = ((hm >> i) & 1ull) ? (unsigned short)0x3F80 : (unsigned short)0;
        #pragma unroll
        for (int i = 0; i < 52; ++i) xrow[52 + i] = ((bm >> i) & 1ull) ? (unsigned short)0x3F80 : (unsigned short)0;
        float feats[15] = { strength, flush_b, straight_b, gr0, gr3, gr4, gr5,
                            valid * flush_draw, valid * flush_outs, valid * straight_draw,
                            valid * straight_outs, valid * equity,
                            valid * hit_pair, valid * hit_trips, valid * hit_two };
        #pragma unroll
        for (int i = 0; i < 15; ++i) xrow[104 + i] = f2bf(feats[i]);
        #pragma unroll
        for (int i = 119; i < 128; ++i) xrow[i] = 0;
    }

    const f32x4 vzero = {0.0f, 0.0f, 0.0f, 0.0f};
    f32x4 acc[4][4];
    #pragma unroll
    for (int a = 0; a < 4; ++a)
        #pragma unroll
        for (int b = 0; b < 4; ++b) acc[a][b] = vzero;

    __syncthreads();

    f32x4 hacc[4];
    float bias;
    // ---- phase A for chunk 0 ----
    {
        #pragma unroll
        for (int mi = 0; mi < 4; ++mi) hacc[mi] = vzero;
        const int ncol = nq * 16 + l16;
        const unsigned short* w1p = W1T + (size_t)ncol * 128 + q * 8;
        #pragma unroll
        for (int ks = 0; ks < 4; ++ks) {
            bf16x8 bfrag = *(const bf16x8*)(w1p + ks * 32);
            #pragma unroll
            for (int mi = 0; mi < 4; ++mi) {
                bf16x8 afrag = *(const bf16x8*)&Xs[R0 + mi * 16 + l16][ks * 32 + q * 8];
                hacc[mi] = __builtin_amdgcn_mfma_f32_16x16x32_bf16(afrag, bfrag, hacc[mi], 0, 0, 0);
            }
        }
        bias = b1[ncol];
        // nothing has read Hs yet this iteration — store directly
        #pragma unroll
        for (int mi = 0; mi < 4; ++mi)
            #pragma unroll
            for (int rg = 0; rg < 4; ++rg)
                Hs[R0 + mi * 16 + q * 4 + rg][nq * 16 + l16] = f2bf(fmaxf(hacc[mi][rg] + bias, 0.0f));
    }

    for (int c = 1; c < 16; ++c) {
        __syncthreads();   // Hs(c-1) visible
        // ---- phase B for chunk c-1 (reads Hs) + phase A for chunk c (registers only) ----
        const unsigned short* w2base = W2T + (size_t)(c - 1) * 64 + q * 8;
        #pragma unroll
        for (int ks = 0; ks < 2; ++ks) {
            bf16x8 afr[4];
            #pragma unroll
            for (int mi = 0; mi < 4; ++mi)
                afr[mi] = *(const bf16x8*)&Hs[R0 + mi * 16 + l16][ks * 32 + q * 8];
            #pragma unroll
            for (int ni = 0; ni < 4; ++ni) {
                bf16x8 bfr = *(const bf16x8*)(w2base + (size_t)(nq * 64 + ni * 16 + l16) * 1024 + ks * 32);
                #pragma unroll
                for (int mi = 0; mi < 4; ++mi)
                    acc[mi][ni] = __builtin_amdgcn_mfma_f32_16x16x32_bf16(afr[mi], bfr, acc[mi][ni], 0, 0, 0);
            }
        }
        {
            #pragma unroll
            for (int mi = 0; mi < 4; ++mi) hacc[mi] = vzero;
            const int ncol = c * 64 + nq * 16 + l16;
            const unsigned short* w1p = W1T + (size_t)ncol * 128 + q * 8;
            #pragma unroll
            for (int ks = 0; ks < 4; ++ks) {
                bf16x8 bfrag = *(const bf16x8*)(w1p + ks * 32);
                #pragma unroll
                for (int mi = 0; mi < 4; ++mi) {
                    bf16x8 afrag = *(const bf16x8*)&Xs[R0 + mi * 16 + l16][ks * 32 + q * 8];
                    hacc[mi] = __builtin_amdgcn_mfma_f32_16x16x32_bf16(afrag, bfrag, hacc[mi], 0, 0, 0);
                }
            }
            bias = b1[ncol];
        }
        __syncthreads();   // all waves done reading Hs(c-1)
        #pragma unroll
        for (int mi = 0; mi < 4; ++mi)
            #pragma unroll
            for (int rg = 0; rg < 4; ++rg)
                Hs[R0 + mi * 16 + q * 4 + rg][nq * 16 + l16] = f2bf(fmaxf(hacc[mi][rg] + bias, 0.0f));
    }

    __syncthreads();
    // ---- phase B for chunk 15 ----
    {
        const unsigned short* w2base = W2T + (size_t)15 * 64 + q * 8;
        #pragma unroll
        for (int ks = 0; ks < 2; ++ks) {
            bf16x8 afr[4];
            #pragma unroll
            for (int mi = 0; mi < 4; ++mi)
                afr[mi] = *(const bf16x8*)&Hs[R0 + mi * 16 + l16][ks * 32 + q * 8];
            #pragma unroll
            for (int ni = 0; ni < 4; ++ni) {
                bf16x8 bfr = *(const bf16x8*)(w2base + (size_t)(nq * 64 + ni * 16 + l16) * 1024 + ks * 32);
                #pragma unroll
                for (int mi = 0; mi < 4; ++mi)
                    acc[mi][ni] = __builtin_amdgcn_mfma_f32_16x16x32_bf16(afr[mi], bfr, acc[mi][ni], 0, 0, 0);
            }
        }
    }

    // ---- epilogue: + b2, store f32 ----
    #pragma unroll
    for (int ni = 0; ni < 4; ++ni) {
        const int n = nq * 64 + ni * 16 + l16;
        const float bb = b2[n];
        #pragma unroll
        for (int mi = 0; mi < 4; ++mi) {
            #pragma unroll
            for (int rg = 0; rg < 4; ++rg) {
                const long row = r0 + R0 + mi * 16 + q * 4 + rg;
                out[row * 256 + n] = acc[mi][ni][rg] + bb;
            }
        }
    }
}

extern "C" void kernel_launch(void* const* d_in, const int* in_sizes, int n_in,
                              void* d_out, int out_size, void* d_ws, size_t ws_size,
                              hipStream_t stream) {
    (void)in_sizes; (void)n_in; (void)out_size; (void)ws_size;
    const float* hole  = (const float*)d_in[0];
    const float* board = (const float*)d_in[1];
    const float* W1    = (const float*)d_in[2];
    const float* b1    = (const float*)d_in[3];
    const float* W2    = (const float*)d_in[4];
    const float* b2    = (const float*)d_in[5];
    float* out = (float*)d_out;

    unsigned short* W1T = (unsigned short*)d_ws;            // 1024*128 bf16 = 256 KB
    unsigned short* W2T = W1T + 1024 * 128;                 // 256*1024 bf16 = 512 KB

    conv_w1<<<512, 256, 0, stream>>>(W1, W1T);
    conv_w2<<<1024, 256, 0, stream>>>(W2, W2T);
    mlp_fused<<<131072 / 128, 512, 0, stream>>>(hole, board, b1, b2, W1T, W2T, out);
}

// Round 3
// 281.914 us; speedup vs baseline: 1.2685x; 1.2685x over previous
//
#include <hip/hip_runtime.h>

typedef __bf16 bf16x8 __attribute__((ext_vector_type(8)));
typedef float f32x16 __attribute__((ext_vector_type(16)));

__device__ __forceinline__ unsigned short f2bf(float f) {
    union { float f; unsigned u; } v; v.f = f;
    unsigned r = (v.u + 0x7FFFu + ((v.u >> 16) & 1u)) >> 16;
    return (unsigned short)r;
}

// ---- weight conversion into MFMA B-fragment order (32x32x16 bf16) ----
// B-frag mapping: lane l holds B[k0 + (l>>5)*8 + j][n0 + (l&31)], j=0..7.
// W1F index = ((g*8 + kb)*64 + l)*8 + j   (g: hidden col-group 0..31, kb: K-step 0..7, K pad 119->128)
__global__ void conv_w1(const float* __restrict__ W1, unsigned short* __restrict__ W1F) {
    int idx = blockIdx.x * 256 + threadIdx.x;          // 131072
    int j = idx & 7, l = (idx >> 3) & 63, kb = (idx >> 9) & 7, g = idx >> 12;
    int k = kb * 16 + (l >> 5) * 8 + j;
    int h = g * 32 + (l & 31);
    float v = (k < 119) ? W1[(size_t)k * 1024 + h] : 0.0f;
    W1F[idx] = f2bf(v);
}
// W2F index = ((gn*64 + kb)*64 + l)*8 + j  (gn: out col-group 0..7, kb: K-step 0..63)
__global__ void conv_w2(const float* __restrict__ W2, unsigned short* __restrict__ W2F) {
    int idx = blockIdx.x * 256 + threadIdx.x;          // 262144
    int j = idx & 7, l = (idx >> 3) & 63, kb = (idx >> 9) & 63, gn = idx >> 15;
    int k = kb * 16 + (l >> 5) * 8 + j;
    int n = gn * 32 + (l & 31);
    W2F[idx] = f2bf(W2[(size_t)k * 256 + n]);
}

// ---- fused features + MLP ----
// 256 threads (4 waves), 64 rows/block, grid 2048. chunk = 128 hidden cols (8 chunks).
// Phase A: H[64x128] = relu(X @ W1chunk + b1): wave w owns col-group cg = c*4+w (1x W1 redundancy),
//          both row-groups -> hacc[2] (32 regs).
// Phase B: acc[64x256] += Hchunk @ W2chunk: wave w owns col-groups {2w,2w+1} (1x W2 redundancy),
//          both row-groups -> acc[2][2] (64 regs).
// All weight loads are fragment-ordered: address = base + lane*16 (fully coalesced).
__global__ __launch_bounds__(256, 4) void mlp_fused(
    const float* __restrict__ hole, const float* __restrict__ board,
    const float* __restrict__ b1, const float* __restrict__ b2,
    const unsigned short* __restrict__ W1F, const unsigned short* __restrict__ W2F,
    float* __restrict__ out)
{
    __shared__ unsigned short Xs[64][136];   // 17408 B; stride 136 shorts (68 dw, +4 banks/row)
    __shared__ unsigned short Hs[64][136];   // 17408 B

    const int tid  = threadIdx.x;
    const int w    = tid >> 6;
    const int lane = tid & 63;
    const int l32  = lane & 31;
    const int hi   = lane >> 5;      // 0/1 half-wave
    const long r0  = (long)blockIdx.x * 64;

    // ---------------- feature extraction: thread t < 64 handles row r0+t ----------------
    if (tid < 64) {
        const long r = r0 + tid;
        const float4* hp = (const float4*)(hole + r * 52);
        const float4* bp = (const float4*)(board + r * 52);
        unsigned long long hm = 0ull, bm = 0ull;
        #pragma unroll
        for (int i = 0; i < 13; ++i) {
            float4 h4 = hp[i], b4 = bp[i];
            int base = i * 4;
            hm |= ((unsigned long long)(h4.x > 0.5f)) << (base + 0);
            hm |= ((unsigned long long)(h4.y > 0.5f)) << (base + 1);
            hm |= ((unsigned long long)(h4.z > 0.5f)) << (base + 2);
            hm |= ((unsigned long long)(h4.w > 0.5f)) << (base + 3);
            bm |= ((unsigned long long)(b4.x > 0.5f)) << (base + 0);
            bm |= ((unsigned long long)(b4.y > 0.5f)) << (base + 1);
            bm |= ((unsigned long long)(b4.z > 0.5f)) << (base + 2);
            bm |= ((unsigned long long)(b4.w > 0.5f)) << (base + 3);
        }
        const unsigned long long am = hm | bm;
        const int bcount = __popcll(bm);
        const int hcount = __popcll(hm);

        int pairs_b = 0, pairs_a = 0;
        bool trips_b = false, trips_a = false;
        unsigned prb = 0, pra = 0;
        #pragma unroll
        for (int rr = 0; rr < 13; ++rr) {
            int cb = __popc((unsigned)((bm >> (4 * rr)) & 0xFull));
            int ca = __popc((unsigned)((am >> (4 * rr)) & 0xFull));
            pairs_b += (cb >= 2); trips_b = trips_b || (cb >= 3); prb |= (unsigned)(cb > 0) << rr;
            pairs_a += (ca >= 2); trips_a = trips_a || (ca >= 3); pra |= (unsigned)(ca > 0) << rr;
        }
        const unsigned long long SM = 0x1111111111111ull;
        int bscm = 0, ascm = 0;
        #pragma unroll
        for (int s = 0; s < 4; ++s) {
            int bs = __popcll(bm & (SM << s));
            int as = __popcll(am & (SM << s));
            bscm = bs > bscm ? bs : bscm;
            ascm = as > ascm ? as : ascm;
        }
        float strength = trips_b ? 0.8f : (pairs_b >= 2 ? 0.6f : (pairs_b >= 1 ? 0.4f : 0.2f));
        if (bcount == 0) strength = 0.0f;
        float flush_b = (bscm >= 3 && bcount > 0) ? 1.0f : 0.0f;
        bool sb = false;
        #pragma unroll
        for (int i = 0; i < 13; ++i) sb = sb || (__popc((prb >> i) & 0x1Fu) >= 3);
        float straight_b = (sb && bcount > 0) ? 1.0f : 0.0f;
        float gr0 = (bcount == 0) ? 1.0f : 0.0f;
        float gr3 = (bcount == 3) ? 1.0f : 0.0f;
        float gr4 = (bcount == 4) ? 1.0f : 0.0f;
        float gr5 = (bcount == 5) ? 1.0f : 0.0f;
        float valid = (hcount >= 2 && bcount >= 1) ? 1.0f : 0.0f;
        float flush_draw = (ascm == 4) ? 1.0f : 0.0f;
        float flush_outs = fmaxf(0.0f, 13.0f - (float)ascm) * (1.0f / 13.0f);
        int first = -1;
        #pragma unroll
        for (int i = 0; i < 13; ++i) {
            bool qq = (((pra >> i) & 1u) != 0u) && (__popc((pra >> i) & 0x1Fu) >= 4);
            if (qq && first < 0) first = i;
        }
        float straight_draw = (first >= 0) ? 1.0f : 0.0f;
        float straight_outs = 0.0f;
        if (first >= 0) {
            int c4 = __popc((pra >> first) & 0xFu);
            straight_outs = (c4 >= 4) ? 0.4f : 0.2f;
        }
        float total_outs = flush_draw * flush_outs * 9.0f + straight_draw * straight_outs * 8.0f;
        float remaining = 52.0f - (float)(hcount + bcount);
        float equity = 0.0f;
        if (remaining > 0.0f) equity = fminf(1.0f, total_outs / fmaxf(remaining, 1.0f));
        float hit_pair  = (pairs_a >= 1) ? 1.0f : 0.0f;
        float hit_trips = trips_a ? 1.0f : 0.0f;
        float hit_two   = (pairs_a >= 2) ? 1.0f : 0.0f;

        unsigned short* xrow = &Xs[tid][0];
        #pragma unroll
        for (int i = 0; i < 52; ++i) xrow[i]      = ((hm >> i) & 1ull) ? (unsigned short)0x3F80 : (unsigned short)0;
        #pragma unroll
        for (int i = 0; i < 52; ++i) xrow[52 + i] = ((bm >> i) & 1ull) ? (unsigned short)0x3F80 : (unsigned short)0;
        float feats[15] = { strength, flush_b, straight_b, gr0, gr3, gr4, gr5,
                            valid * flush_draw, valid * flush_outs, valid * straight_draw,
                            valid * straight_outs, valid * equity,
                            valid * hit_pair, valid * hit_trips, valid * hit_two };
        #pragma unroll
        for (int i = 0; i < 15; ++i) xrow[104 + i] = f2bf(feats[i]);
        #pragma unroll
        for (int i = 119; i < 128; ++i) xrow[i] = 0;
    }

    f32x16 acc[2][2];
    #pragma unroll
    for (int a = 0; a < 2; ++a)
        #pragma unroll
        for (int b = 0; b < 2; ++b)
            #pragma unroll
            for (int r = 0; r < 16; ++r) acc[a][b][r] = 0.0f;

    __syncthreads();

    f32x16 hacc[2];
    float bias;

    // ---- phase A, chunk 0 ----
    {
        #pragma unroll
        for (int mi = 0; mi < 2; ++mi)
            #pragma unroll
            for (int r = 0; r < 16; ++r) hacc[mi][r] = 0.0f;
        const unsigned short* w1p = W1F + ((size_t)(0 * 4 + w) * 8) * 512 + lane * 8;
        #pragma unroll
        for (int ks = 0; ks < 8; ++ks) {
            bf16x8 bfr = *(const bf16x8*)(w1p + ks * 512);
            bf16x8 a0 = *(const bf16x8*)&Xs[l32][ks * 16 + hi * 8];
            bf16x8 a1 = *(const bf16x8*)&Xs[32 + l32][ks * 16 + hi * 8];
            hacc[0] = __builtin_amdgcn_mfma_f32_32x32x16_bf16(a0, bfr, hacc[0], 0, 0, 0);
            hacc[1] = __builtin_amdgcn_mfma_f32_32x32x16_bf16(a1, bfr, hacc[1], 0, 0, 0);
        }
        bias = b1[w * 32 + l32];
        #pragma unroll
        for (int mi = 0; mi < 2; ++mi)
            #pragma unroll
            for (int r = 0; r < 16; ++r) {
                int row = mi * 32 + (r & 3) + 8 * (r >> 2) + 4 * hi;
                Hs[row][w * 32 + l32] = f2bf(fmaxf(hacc[mi][r] + bias, 0.0f));
            }
    }

    for (int c = 1; c < 8; ++c) {
        __syncthreads();    // Hs(c-1) visible
        // ---- phase B, chunk c-1 (reads Hs) + phase A, chunk c (registers only) ----
        {
            const unsigned short* w2p0 = W2F + ((size_t)(2 * w + 0) * 64 + (c - 1) * 8) * 512 + lane * 8;
            const unsigned short* w2p1 = W2F + ((size_t)(2 * w + 1) * 64 + (c - 1) * 8) * 512 + lane * 8;
            #pragma unroll
            for (int ks = 0; ks < 8; ++ks) {
                bf16x8 a0 = *(const bf16x8*)&Hs[l32][ks * 16 + hi * 8];
                bf16x8 a1 = *(const bf16x8*)&Hs[32 + l32][ks * 16 + hi * 8];
                bf16x8 bf0 = *(const bf16x8*)(w2p0 + ks * 512);
                bf16x8 bf1 = *(const bf16x8*)(w2p1 + ks * 512);
                acc[0][0] = __builtin_amdgcn_mfma_f32_32x32x16_bf16(a0, bf0, acc[0][0], 0, 0, 0);
                acc[0][1] = __builtin_amdgcn_mfma_f32_32x32x16_bf16(a0, bf1, acc[0][1], 0, 0, 0);
                acc[1][0] = __builtin_amdgcn_mfma_f32_32x32x16_bf16(a1, bf0, acc[1][0], 0, 0, 0);
                acc[1][1] = __builtin_amdgcn_mfma_f32_32x32x16_bf16(a1, bf1, acc[1][1], 0, 0, 0);
            }
        }
        {
            #pragma unroll
            for (int mi = 0; mi < 2; ++mi)
                #pragma unroll
                for (int r = 0; r < 16; ++r) hacc[mi][r] = 0.0f;
            const unsigned short* w1p = W1F + ((size_t)(c * 4 + w) * 8) * 512 + lane * 8;
            #pragma unroll
            for (int ks = 0; ks < 8; ++ks) {
                bf16x8 bfr = *(const bf16x8*)(w1p + ks * 512);
                bf16x8 a0 = *(const bf16x8*)&Xs[l32][ks * 16 + hi * 8];
                bf16x8 a1 = *(const bf16x8*)&Xs[32 + l32][ks * 16 + hi * 8];
                hacc[0] = __builtin_amdgcn_mfma_f32_32x32x16_bf16(a0, bfr, hacc[0], 0, 0, 0);
                hacc[1] = __builtin_amdgcn_mfma_f32_32x32x16_bf16(a1, bfr, hacc[1], 0, 0, 0);
            }
            bias = b1[c * 128 + w * 32 + l32];
        }
        __syncthreads();    // all waves done reading Hs(c-1)
        #pragma unroll
        for (int mi = 0; mi < 2; ++mi)
            #pragma unroll
            for (int r = 0; r < 16; ++r) {
                int row = mi * 32 + (r & 3) + 8 * (r >> 2) + 4 * hi;
                Hs[row][w * 32 + l32] = f2bf(fmaxf(hacc[mi][r] + bias, 0.0f));
            }
    }

    __syncthreads();
    // ---- phase B, chunk 7 ----
    {
        const unsigned short* w2p0 = W2F + ((size_t)(2 * w + 0) * 64 + 7 * 8) * 512 + lane * 8;
        const unsigned short* w2p1 = W2F + ((size_t)(2 * w + 1) * 64 + 7 * 8) * 512 + lane * 8;
        #pragma unroll
        for (int ks = 0; ks < 8; ++ks) {
            bf16x8 a0 = *(const bf16x8*)&Hs[l32][ks * 16 + hi * 8];
            bf16x8 a1 = *(const bf16x8*)&Hs[32 + l32][ks * 16 + hi * 8];
            bf16x8 bf0 = *(const bf16x8*)(w2p0 + ks * 512);
            bf16x8 bf1 = *(const bf16x8*)(w2p1 + ks * 512);
            acc[0][0] = __builtin_amdgcn_mfma_f32_32x32x16_bf16(a0, bf0, acc[0][0], 0, 0, 0);
            acc[0][1] = __builtin_amdgcn_mfma_f32_32x32x16_bf16(a0, bf1, acc[0][1], 0, 0, 0);
            acc[1][0] = __builtin_amdgcn_mfma_f32_32x32x16_bf16(a1, bf0, acc[1][0], 0, 0, 0);
            acc[1][1] = __builtin_amdgcn_mfma_f32_32x32x16_bf16(a1, bf1, acc[1][1], 0, 0, 0);
        }
    }

    // ---- epilogue: + b2, store f32 ----
    #pragma unroll
    for (int ni = 0; ni < 2; ++ni) {
        const int col = (2 * w + ni) * 32 + l32;
        const float bb = b2[col];
        #pragma unroll
        for (int mi = 0; mi < 2; ++mi) {
            #pragma unroll
            for (int r = 0; r < 16; ++r) {
                const long row = r0 + mi * 32 + (r & 3) + 8 * (r >> 2) + 4 * hi;
                out[row * 256 + col] = acc[mi][ni][r] + bb;
            }
        }
    }
}

extern "C" void kernel_launch(void* const* d_in, const int* in_sizes, int n_in,
                              void* d_out, int out_size, void* d_ws, size_t ws_size,
                              hipStream_t stream) {
    (void)in_sizes; (void)n_in; (void)out_size; (void)ws_size;
    const float* hole  = (const float*)d_in[0];
    const float* board = (const float*)d_in[1];
    const float* W1    = (const float*)d_in[2];
    const float* b1    = (const float*)d_in[3];
    const float* W2    = (const float*)d_in[4];
    const float* b2    = (const float*)d_in[5];
    float* out = (float*)d_out;

    unsigned short* W1F = (unsigned short*)d_ws;            // 131072 bf16 = 256 KB
    unsigned short* W2F = W1F + 131072;                     // 262144 bf16 = 512 KB

    conv_w1<<<512, 256, 0, stream>>>(W1, W1F);
    conv_w2<<<1024, 256, 0, stream>>>(W2, W2F);
    mlp_fused<<<131072 / 64, 256, 0, stream>>>(hole, board, b1, b2, W1F, W2F, out);
}